// Round 6
// baseline (1028.914 us; speedup 1.0000x reference)
//
#include <hip/hip_runtime.h>
#include <math.h>

#define NB 16384
typedef unsigned short ushort_t;
typedef unsigned int uint_t;
typedef __attribute__((ext_vector_type(8))) short short8;
typedef __attribute__((ext_vector_type(4))) float fx4;
typedef _Float16 half2v __attribute__((ext_vector_type(2)));
typedef _Float16 half4v __attribute__((ext_vector_type(4)));

// ---- ws float offsets ----
static const size_t OFF_HB    = 0;          // ushort[16384*1568] bf16, pixel-major [p49][ci32]
static const size_t OFF_F1B   = 12845056;   // ushort[16384*224]
static const size_t OFF_F3B   = 14680064;   // ushort[16384*224]
static const size_t OFF_Z     = 16515072;   // float[524288]
static const size_t OFF_IDX   = 17039360;   // int[16384]
static const size_t OFF_ZQB   = 17055744;   // ushort[524288]
static const size_t OFF_CNT   = 17317888;   // float[512]
static const size_t OFF_SUM   = 17318400;   // float[16384]
static const size_t OFF_LOSS  = 17334784;   // float[64]
static const size_t OFF_WENC  = 17334848;   // ushort[8192] [8kb][32co][32k]
static const size_t OFF_WT1B  = 17343040;   // ushort[8192] [16kk][16co][32ci]
static const size_t OFF_WR1B  = 17351232;   // ushort[18432]  [9][64][32]
static const size_t OFF_WR2B  = 17360448;   // ushort[18432]
static const size_t OFF_W2B1  = 17369664;   // ushort[2048]   [32][64]
static const size_t OFF_W2B2  = 17370688;   // ushort[2048]
static const size_t OFF_FC1WB = 17371712;   // ushort[351232] [224][1568 k-permuted]
static const size_t OFF_FC2WB = 17547328;   // ushort[7168]   [32][224]
static const size_t OFF_FC3WB = 17550912;   // ushort[7168]   [224][32]
static const size_t OFF_FC4WB = 17554496;   // ushort[351232] [1568 n-permuted][224]
static const size_t OFF_FC4BP = 17730112;   // float[1568] permuted fc4 bias
static const size_t OFF_WENC1 = 17731680;   // ushort[512] conv1 [16co][32k] (k>=16 zero)

static __device__ __forceinline__ ushort_t f2bf(float f) {
  union { float f; uint_t u; } v; v.f = f;
  return (ushort_t)((v.u + 0x7fffu + ((v.u >> 16) & 1u)) >> 16);
}
static __device__ __forceinline__ float bf2f(ushort_t h) {
  union { uint_t u; float f; } v; v.u = ((uint_t)h) << 16;
  return v.f;
}
static __device__ __forceinline__ float fdot2(half2v a, half2v b, float c) {
#if __has_builtin(__builtin_amdgcn_fdot2)
  return __builtin_amdgcn_fdot2(a, b, c, false);
#else
  return c + (float)a.x * (float)b.x + (float)a.y * (float)b.y;
#endif
}

// Weight prep: transposes, permutes, fp32->bf16; zero loss accumulator.
__global__ __launch_bounds__(256) void k_prep(
    const float* __restrict__ c1w, const float* __restrict__ c2w,
    const float* __restrict__ r1w1, const float* __restrict__ r1w2,
    const float* __restrict__ r2w1, const float* __restrict__ r2w2,
    const float* __restrict__ t1w,
    const float* __restrict__ fc1w, const float* __restrict__ fc2w,
    const float* __restrict__ fc3w, const float* __restrict__ fc4w,
    const float* __restrict__ fc4b, float* __restrict__ ws)
{
  int gid = blockIdx.x * 256 + threadIdx.x;
  if (gid == 0) ws[OFF_LOSS] = 0.f;
  if (gid >= 776224) return;
  ushort_t* wencb = (ushort_t*)(ws + OFF_WENC);
  ushort_t* wt1b  = (ushort_t*)(ws + OFF_WT1B);
  ushort_t* wr1b  = (ushort_t*)(ws + OFF_WR1B);
  ushort_t* wr2b  = (ushort_t*)(ws + OFF_WR2B);
  ushort_t* w2b1  = (ushort_t*)(ws + OFF_W2B1);
  ushort_t* w2b2  = (ushort_t*)(ws + OFF_W2B2);
  ushort_t* fc1wb = (ushort_t*)(ws + OFF_FC1WB);
  ushort_t* fc2wb = (ushort_t*)(ws + OFF_FC2WB);
  ushort_t* fc3wb = (ushort_t*)(ws + OFF_FC3WB);
  ushort_t* fc4wb = (ushort_t*)(ws + OFF_FC4WB);
  float*    fc4bp = ws + OFF_FC4BP;
  ushort_t* wenc1b = (ushort_t*)(ws + OFF_WENC1);
  int i = gid;
  if (i < 8192) {            // conv2 MFMA weights: [kb=ky*2+k2][co32][k=kxs*16+ci]
    int kidx = i & 31, rest = i >> 5, co = rest & 31, kb = rest >> 5;
    int ky = kb >> 1, k2 = kb & 1, kxs = kidx >> 4, ci = kidx & 15;
    wencb[i] = f2bf(c2w[co*256 + ci*16 + ky*4 + 2*k2 + kxs]);
  } else if (i < 16384) {    // convT1 MFMA weights: [kk16][co16][ci32]
    int j = i - 8192, ci = j & 31, rest = j >> 5, co = rest & 15, kk = rest >> 4;
    wt1b[j] = f2bf(t1w[ci*256 + co*16 + kk]);
  } else if (i < 34816) {    // res1 w1 -> [kk][co][ci] bf16
    int j = i - 16384, ci = j & 31, r = j >> 5, co = r & 63, kk = r >> 6;
    wr1b[j] = f2bf(r1w1[co*288 + ci*9 + kk]);
  } else if (i < 53248) {    // res2 w1
    int j = i - 34816, ci = j & 31, r = j >> 5, co = r & 63, kk = r >> 6;
    wr2b[j] = f2bf(r2w1[co*288 + ci*9 + kk]);
  } else if (i < 55296) {    // res1 w2 [32][64] bf16
    int j = i - 53248; w2b1[j] = f2bf(r1w2[j]);
  } else if (i < 57344) {    // res2 w2
    int j = i - 55296; w2b2[j] = f2bf(r2w2[j]);
  } else if (i < 408576) {   // fc1 [224][1568], K permuted: k' = p*32+ci <- ci*49+p
    int j = i - 57344, n = j / 1568, k = j % 1568;
    int p = k >> 5, ci = k & 31;
    fc1wb[j] = f2bf(fc1w[n*1568 + ci*49 + p]);
  } else if (i < 415744) {   // fc2 [32][224]
    int j = i - 408576; fc2wb[j] = f2bf(fc2w[j]);
  } else if (i < 422912) {   // fc3 [224][32]
    int j = i - 415744; fc3wb[j] = f2bf(fc3w[j]);
  } else if (i < 774144) {   // fc4 [1568][224], N permuted: row p*32+ci <- ci*49+p
    int j = i - 422912, np = j / 224, k = j % 224;
    int p = np >> 5, ci = np & 31;
    fc4wb[j] = f2bf(fc4w[(ci*49 + p)*224 + k]);
  } else if (i < 775712) {   // fc4 bias permuted
    int np = i - 774144, p = np >> 5, ci = np & 31;
    fc4bp[np] = fc4b[ci*49 + p];
  } else {                   // conv1 MFMA weights: [co16][k32], taps 16..31 zero
    int j = i - 775712, k = j & 31, co = j >> 5;
    wenc1b[j] = (k < 16) ? f2bf(c1w[co*16 + k]) : (ushort_t)0;
  }
}

// Fused encoder: conv1 (MFMA via im2col, K_real=16) -> relu -> conv2 (MFMA).
// Output pixel-major bf16 [p49][ci32]. One image/block, 256 threads.
__global__ __launch_bounds__(256) void k_enc(const float* __restrict__ x,
    const ushort_t* __restrict__ wenc1b, const float* __restrict__ b1,
    const ushort_t* __restrict__ wencb, const float* __restrict__ b2,
    ushort_t* __restrict__ hb)
{
  __shared__ float xin[30][32];          // x padded
  __shared__ ushort_t icb[208*32];       // im2col [pix208][k32] bf16, swizzled 64B rows
  __shared__ ushort_t ph1b[256*24];      // h1 [prow=piy*16+pix][ci16] bf16, 48B rows
  __shared__ ushort_t outl[1568];        // [p49][co32]
  int b = blockIdx.x, t = threadIdx.x, l = t & 63, w = t >> 6;
  int pr = l & 15, g = l >> 4;
  // B-frags
  short8 bf1 = *(const short8*)(wenc1b + (size_t)pr*32 + g*8);
  short8 bf[8][2];
  #pragma unroll
  for (int kb = 0; kb < 8; ++kb)
    #pragma unroll
    for (int nt = 0; nt < 2; ++nt)
      bf[kb][nt] = *(const short8*)(wencb + (size_t)(kb*32 + nt*16 + pr)*32 + g*8);
  float bv1 = b1[pr];
  // zero LDS
  uint_t* iz = (uint_t*)icb;
  for (int i = t; i < 3328; i += 256) iz[i] = 0;
  uint_t* pz = (uint_t*)ph1b;
  for (int i = t; i < 3072; i += 256) pz[i] = 0;
  float* xp = &xin[0][0];
  for (int i = t; i < 960; i += 256) xp[i] = 0.f;
  __syncthreads();
  const float* xb = x + (size_t)b*784;
  for (int i = t; i < 784; i += 256) xin[i/28 + 1][i%28 + 1] = xb[i];
  __syncthreads();
  // build im2col: entry (pixel p, tap k) = xin[2*(p/14)+k/4][2*(p%14)+k%4]
  char* icc = (char*)icb;
  for (int i = t; i < 3136; i += 256) {
    int p = i >> 4, k = i & 15;
    int oy = p / 14, ox = p % 14;
    float v = xin[2*oy + (k >> 2)][2*ox + (k & 3)];
    int byte = ((p << 6) + (k << 1)) ^ ((p & 6) << 3);
    *(ushort_t*)(icc + byte) = f2bf(v);
  }
  __syncthreads();
  // conv1 MFMA: 13 M-tiles over 196 pixels, N=16 co, 1 K-step
  char* phc = (char*)ph1b;
  #pragma unroll
  for (int mq = 0; mq < 4; ++mq) {
    int mt = w + mq*4;
    if (mt > 12) continue;             // wave-uniform
    fx4 a1 = (fx4){0.f, 0.f, 0.f, 0.f};
    int arow = mt*16 + pr;
    int byte = ((arow << 6) + (g << 4)) ^ ((arow & 6) << 3);
    short8 af = *(const short8*)(icc + byte);
    a1 = __builtin_amdgcn_mfma_f32_16x16x32_bf16(af, bf1, a1, 0, 0, 0);
    #pragma unroll
    for (int i = 0; i < 4; ++i) {
      int pix = mt*16 + g*4 + i;
      if (pix < 196) {
        int prow = (pix/14 + 1)*16 + (pix%14) + 1;
        *(ushort_t*)(phc + prow*48 + pr*2) = f2bf(fmaxf(a1[i] + bv1, 0.f));
      }
    }
  }
  __syncthreads();
  // conv2 MFMA: wave w = M-tile; 8 k-blocks, 2 n-tiles
  int p = w*16 + pr; if (p > 48) p = 48;
  int oy = p/7, ox = p%7;
  fx4 acc2[2];
  acc2[0] = (fx4){0.f,0.f,0.f,0.f}; acc2[1] = (fx4){0.f,0.f,0.f,0.f};
  #pragma unroll
  for (int kb = 0; kb < 8; ++kb) {
    int ky = kb >> 1, k2 = kb & 1;
    int prow = (2*oy + ky)*16 + 2*ox + 2*k2 + (g >> 1);
    short8 afr = *(const short8*)(phc + prow*48 + (g & 1)*16);
    acc2[0] = __builtin_amdgcn_mfma_f32_16x16x32_bf16(afr, bf[kb][0], acc2[0], 0, 0, 0);
    acc2[1] = __builtin_amdgcn_mfma_f32_16x16x32_bf16(afr, bf[kb][1], acc2[1], 0, 0, 0);
  }
  #pragma unroll
  for (int nt = 0; nt < 2; ++nt) {
    int co = nt*16 + pr;
    float bv = b2[co];
    #pragma unroll
    for (int i = 0; i < 4; ++i) {
      int pix = w*16 + g*4 + i;
      if (pix < 49) outl[pix*32 + co] = f2bf(acc2[nt][i] + bv);
    }
  }
  __syncthreads();
  uint_t* dst = (uint_t*)(hb + (size_t)b*1568);
  const uint_t* so = (const uint_t*)outl;
  for (int j = t; j < 784; j += 256) dst[j] = so[j];
}

// MFMA residual stack, pixel-major in/out bf16 [p49][ci32], in-place.
__global__ __launch_bounds__(256) void k_res(ushort_t* __restrict__ hb,
    const ushort_t* __restrict__ wrb, const ushort_t* __restrict__ w2b)
{
  __shared__ ushort_t pinT[3456];   // [pp=108][ci=32], swizzled (64B rows)
  __shared__ ushort_t rl[4096];     // [pix=64][co=64], swizzled (128B rows)
  __shared__ ushort_t hrawb[1568];  // raw copy, [p][ci]
  __shared__ ushort_t outl[1568];   // [p][ci]
  int b = blockIdx.x, t = threadIdx.x, l = t & 63, w = t >> 6, g = l >> 4;

  short8 bfr[9];
  #pragma unroll
  for (int o = 0; o < 9; ++o)
    bfr[o] = *(const short8*)(wrb + (size_t)(o*64 + w*16 + (l & 15))*32 + g*8);

  uint_t* pz = (uint_t*)pinT;
  for (int i = t; i < 1728; i += 256) pz[i] = 0;
  __syncthreads();

  const uint_t* src = (const uint_t*)(hb + (size_t)b*1568);
  char* pinc = (char*)pinT;
  for (int j = t; j < 784; j += 256) {
    uint_t u = src[j];
    ((uint_t*)hrawb)[j] = u;
    uint_t ur = u;
    ur = (ur & 0x80000000u) ? (ur & 0x0000ffffu) : ur;   // relu hi half
    ur = (ur & 0x8000u)     ? (ur & 0xffff0000u) : ur;   // relu lo half
    int p = j >> 4, c2 = (j & 15) << 1;
    int ppix = (p/7 + 1)*12 + (p%7) + 1;
    int byte = ((ppix << 6) + (c2 << 1)) ^ ((ppix & 6) << 3);
    *(uint_t*)(pinc + byte) = ur;
  }
  __syncthreads();

  fx4 acc[4];
  #pragma unroll
  for (int mt = 0; mt < 4; ++mt) acc[mt] = (fx4){0.f, 0.f, 0.f, 0.f};
  int pb[4];
  #pragma unroll
  for (int mt = 0; mt < 4; ++mt) {
    int p = mt*16 + (l & 15); if (p > 48) p = 48;
    pb[mt] = (p / 7)*12 + (p % 7);
  }
  #pragma unroll
  for (int mt = 0; mt < 4; ++mt) {
    #pragma unroll
    for (int o = 0; o < 9; ++o) {
      int ppix = pb[mt] + (o / 3)*12 + (o % 3);
      int byte = ((ppix << 6) + (g << 4)) ^ ((ppix & 6) << 3);
      short8 afr = *(const short8*)(pinc + byte);
      acc[mt] = __builtin_amdgcn_mfma_f32_16x16x32_bf16(afr, bfr[o], acc[mt], 0, 0, 0);
    }
  }
  char* rlc = (char*)rl;
  #pragma unroll
  for (int mt = 0; mt < 4; ++mt) {
    #pragma unroll
    for (int i = 0; i < 4; ++i) {
      int pixr = mt*16 + g*4 + i;
      int co2 = w*16 + (l & 15);
      int byte = ((pixr << 7) + (co2 << 1)) ^ ((pixr & 7) << 4);
      *(ushort_t*)(rlc + byte) = f2bf(fmaxf(acc[mt][i], 0.f));
    }
  }
  __syncthreads();

  fx4 a1[2];
  a1[0] = (fx4){0.f,0.f,0.f,0.f}; a1[1] = (fx4){0.f,0.f,0.f,0.f};
  int prr = w*16 + (l & 15);
  #pragma unroll
  for (int kf = 0; kf < 2; ++kf) {
    int byte = ((prr << 7) + (kf << 6) + (g << 4)) ^ ((prr & 7) << 4);
    short8 ar = *(const short8*)(rlc + byte);
    #pragma unroll
    for (int nt = 0; nt < 2; ++nt) {
      short8 br = *(const short8*)(w2b + (size_t)(nt*16 + (l & 15))*64 + kf*32 + g*8);
      a1[nt] = __builtin_amdgcn_mfma_f32_16x16x32_bf16(ar, br, a1[nt], 0, 0, 0);
    }
  }
  #pragma unroll
  for (int nt = 0; nt < 2; ++nt) {
    #pragma unroll
    for (int i = 0; i < 4; ++i) {
      int pix = w*16 + g*4 + i;
      if (pix < 49) {
        int co2 = nt*16 + (l & 15);
        int idx2 = pix*32 + co2;
        float v = bf2f(hrawb[idx2]) + a1[nt][i];
        outl[idx2] = f2bf(fmaxf(v, 0.f));
      }
    }
  }
  __syncthreads();
  uint_t* dst = (uint_t*)(hb + (size_t)b*1568);
  const uint_t* so = (const uint_t*)outl;
  for (int j = t; j < 784; j += 256) dst[j] = so[j];
}

// MFMA GEMM with A-prefetch: C[M,N] = A[M,K](bf16) * Wb[N,K]^T + bias.
template<int BNF, bool OUTBF16, bool RELU>
__global__ __launch_bounds__(256) void k_mm(const ushort_t* __restrict__ A,
    const ushort_t* __restrict__ Wb, const float* __restrict__ bias,
    void* __restrict__ C, int M, int N, int K)
{
  __shared__ ushort_t As[2048];   // [64][32] bf16, swizzled (64B rows)
  int t = threadIdx.x, l = t & 63, w = t >> 6, g = l >> 4;
  int m0 = blockIdx.x * 64, n0 = blockIdx.y * (BNF * 16);
  fx4 acc[BNF];
  #pragma unroll
  for (int nt = 0; nt < BNF; ++nt) acc[nt] = (fx4){0.f, 0.f, 0.f, 0.f};
  char* asc = (char*)As;
  int srow = t >> 2, sks = (t & 3) * 8;
  int sbyte = ((srow << 6) + (sks << 1)) ^ ((srow & 6) << 3);
  int arow = w*16 + (l & 15);
  int abyte = ((arow << 6) + (g << 4)) ^ ((arow & 6) << 3);
  const ushort_t* ap = A + (size_t)(m0 + srow)*K + sks;
  short8 av = *(const short8*)ap;
  for (int k0 = 0; k0 < K; k0 += 32) {
    __syncthreads();
    *(short8*)(asc + sbyte) = av;
    __syncthreads();
    if (k0 + 32 < K) av = *(const short8*)(ap + k0 + 32);   // prefetch next
    short8 afr = *(const short8*)(asc + abyte);
    #pragma unroll
    for (int nt = 0; nt < BNF; ++nt) {
      short8 bfr = *(const short8*)(Wb + (size_t)(n0 + nt*16 + (l & 15))*K + k0 + g*8);
      acc[nt] = __builtin_amdgcn_mfma_f32_16x16x32_bf16(afr, bfr, acc[nt], 0, 0, 0);
    }
  }
  #pragma unroll
  for (int nt = 0; nt < BNF; ++nt) {
    int col = n0 + nt*16 + (l & 15);
    float bv = bias[col];
    #pragma unroll
    for (int i = 0; i < 4; ++i) {
      int row = m0 + w*16 + g*4 + i;
      float v = acc[nt][i] + bv;
      if (RELU) v = fmaxf(v, 0.f);
      if (OUTBF16) ((ushort_t*)C)[(size_t)row*N + col] = f2bf(v);
      else         ((float*)C)[(size_t)row*N + col] = v;
    }
  }
}

// VQ assign: one wave per row; 64 lanes split 512 codes (8 each), shfl argmin.
// 4096 blocks x 256 threads (4 rows/block).
__global__ __launch_bounds__(256) void k_vq_assign(const float* __restrict__ z,
    const float* __restrict__ emb, ushort_t* __restrict__ zqb, int* __restrict__ idx,
    float* __restrict__ loss)
{
  __shared__ float lred[4];
  int t = threadIdx.x, w = t >> 6, ln = t & 63;
  int n = blockIdx.x * 4 + w;
  // z row into registers (static-indexed)
  float zv[32];
  const float4* zp = (const float4*)&z[(size_t)n*32];
  float zz = 0.f;
  #pragma unroll
  for (int q = 0; q < 8; ++q) {
    float4 v = zp[q];
    zv[4*q]=v.x; zv[4*q+1]=v.y; zv[4*q+2]=v.z; zv[4*q+3]=v.w;
    zz += v.x*v.x + v.y*v.y + v.z*v.z + v.w*v.w;
  }
  float best = 3.4e38f; int bi = 0x7fffffff;
  #pragma unroll
  for (int c = 0; c < 8; ++c) {
    int e = c*64 + ln;
    const float4* ep = (const float4*)&emb[(size_t)e*32];
    float dot = 0.f, es = 0.f;
    #pragma unroll
    for (int q = 0; q < 8; ++q) {
      float4 v = ep[q];
      dot += zv[4*q]*v.x + zv[4*q+1]*v.y + zv[4*q+2]*v.z + zv[4*q+3]*v.w;
      es  += v.x*v.x + v.y*v.y + v.z*v.z + v.w*v.w;
    }
    float d = zz + es - 2.f*dot;
    if (d < best) { best = d; bi = e; }
  }
  // wave argmin, ties -> smallest index (matches first-occurrence argmin)
  #pragma unroll
  for (int m = 32; m >= 1; m >>= 1) {
    float ob = __shfl_xor(best, m);
    int   oi = __shfl_xor(bi, m);
    if (ob < best || (ob == best && oi < bi)) { best = ob; bi = oi; }
  }
  if (ln == 0) idx[n] = bi;
  // cooperative zq gather (lane=dim) + commit loss
  int dim = ln & 31;
  float ev = emb[(size_t)bi*32 + dim];
  float evh = __shfl_xor(ev, 1);
  if (ln < 32 && !(ln & 1))
    ((uint_t*)(zqb + (size_t)n*32))[ln >> 1] = (uint_t)f2bf(ev) | ((uint_t)f2bf(evh) << 16);
  float ls = 0.f;
  if (ln < 32) { float d = ev - z[(size_t)n*32 + dim]; ls = d*d; }
  #pragma unroll
  for (int m = 32; m >= 1; m >>= 1) ls += __shfl_xor(ls, m);
  if (ln == 0) lred[w] = ls;
  __syncthreads();
  if (t == 0) atomicAdd(loss, lred[0] + lred[1] + lred[2] + lred[3]);
}

// Per-code segment reduction: counts[e], sums[e][32]. One wave per code.
__global__ __launch_bounds__(64) void k_vq_reduce(const int* __restrict__ idx,
    const float* __restrict__ z, float* __restrict__ counts, float* __restrict__ sums)
{
  int e = blockIdx.x, t = threadIdx.x;
  float cnt = 0.f, sv[32];
  #pragma unroll
  for (int k = 0; k < 32; ++k) sv[k] = 0.f;
  for (int n = t; n < 16384; n += 64) {
    if (idx[n] == e) {
      cnt += 1.f;
      const float4* zp = (const float4*)&z[n*32];
      #pragma unroll
      for (int q = 0; q < 8; ++q) {
        float4 v = zp[q];
        sv[4*q] += v.x; sv[4*q+1] += v.y; sv[4*q+2] += v.z; sv[4*q+3] += v.w;
      }
    }
  }
  #pragma unroll
  for (int m = 32; m >= 1; m >>= 1) {
    cnt += __shfl_xor(cnt, m);
    #pragma unroll
    for (int k = 0; k < 32; ++k) sv[k] += __shfl_xor(sv[k], m);
  }
  if (t == 0) {
    counts[e] = cnt;
    #pragma unroll
    for (int k = 0; k < 32; ++k) sums[e*32 + k] = sv[k];
  }
}

// EMA update, emb_new, perplexity, losses.
__global__ __launch_bounds__(512) void k_vq_final(const float* __restrict__ counts,
    const float* __restrict__ sums, const float* __restrict__ n_mat,
    const float* __restrict__ m_mat, const float* __restrict__ loss,
    float* __restrict__ out)
{
  __shared__ float red[8];
  int t = threadIdx.x;
  float c = counts[t];
  float nn = n_mat[t]*0.99f + c*0.01f;
  #pragma unroll
  for (int k = 0; k < 32; ++k) {
    float mn = m_mat[t*32+k]*0.99f + sums[t*32+k]*0.01f;
    out[12845059 + t*32 + k] = mn / nn;
  }
  float em = c * (1.f/16384.f);
  float ht = em * logf(em + 1e-10f);
  #pragma unroll
  for (int m = 32; m >= 1; m >>= 1) ht += __shfl_xor(ht, m);
  if ((t & 63) == 0) red[t >> 6] = ht;
  __syncthreads();
  if (t == 0) {
    float H = 0.f;
    #pragma unroll
    for (int i = 0; i < 8; ++i) H += red[i];
    float q = loss[0] * (1.f/524288.f);
    out[12845056] = q;           // quant_loss
    out[12845057] = q;           // commit_loss (BETA = 1.0)
    out[12845058] = expf(-H);    // perplexity
  }
}

// Fused decoder: convT1 (MFMA, parity/wave) -> relu -> convT2 (fdot2 on f16).
// Input pixel-major bf16 [p49][ci32]; output fp32 [784]. One image/block.
__global__ __launch_bounds__(256) void k_dec(const ushort_t* __restrict__ h5,
    const ushort_t* __restrict__ wt1b, const float* __restrict__ bt1,
    const float* __restrict__ wt2, const float* __restrict__ bt2,
    float* __restrict__ out)
{
  __shared__ ushort_t pinT[3456];     // h5 [ppix=108][ci=32] swizzled (64B rows)
  __shared__ ushort_t pt1b[256*20];   // t1 [opix=(iy+1)*16+(ix+1)][ci16] f16, 40B stride
  __shared__ float w2l[256];          // convT2 weights [ci][kk] fp32
  __shared__ float outl[784];
  int b = blockIdx.x, t = threadIdx.x, l = t & 63, w = t >> 6;
  int pr = l & 15, g = l >> 4;
  int py = w >> 1, px = w & 1;        // wave parity
  short8 bfr[4];
  #pragma unroll
  for (int r = 0; r < 2; ++r)
    #pragma unroll
    for (int c = 0; c < 2; ++c) {
      int kk = (3 - py - 2*r)*4 + (3 - px - 2*c);
      bfr[r*2 + c] = *(const short8*)(wt1b + (size_t)(kk*16 + pr)*32 + g*8);
    }
  uint_t* pz = (uint_t*)pinT;
  for (int i = t; i < 1728; i += 256) pz[i] = 0;
  uint_t* qz = (uint_t*)pt1b;
  for (int i = t; i < 2560; i += 256) qz[i] = 0;
  if (t < 256) w2l[t] = wt2[t];
  __syncthreads();
  const uint_t* src = (const uint_t*)(h5 + (size_t)b*1568);
  char* pinc = (char*)pinT;
  for (int j = t; j < 784; j += 256) {
    uint_t u = src[j];
    int p = j >> 4, c2 = (j & 15) << 1;
    int ppix = (p/7 + 1)*12 + (p%7) + 1;
    int byte = ((ppix << 6) + (c2 << 1)) ^ ((ppix & 6) << 3);
    *(uint_t*)(pinc + byte) = u;
  }
  __syncthreads();
  fx4 acc[4];
  #pragma unroll
  for (int mt = 0; mt < 4; ++mt) acc[mt] = (fx4){0.f, 0.f, 0.f, 0.f};
  int pb[4];
  #pragma unroll
  for (int mt = 0; mt < 4; ++mt) {
    int p = mt*16 + pr; if (p > 48) p = 48;
    pb[mt] = (p / 7)*12 + (p % 7);
  }
  #pragma unroll
  for (int mt = 0; mt < 4; ++mt) {
    #pragma unroll
    for (int r = 0; r < 2; ++r)
      #pragma unroll
      for (int c = 0; c < 2; ++c) {
        int ppix = pb[mt] + (py + r)*12 + (px + c);
        int byte = ((ppix << 6) + (g << 4)) ^ ((ppix & 6) << 3);
        short8 afr = *(const short8*)(pinc + byte);
        acc[mt] = __builtin_amdgcn_mfma_f32_16x16x32_bf16(afr, bfr[r*2 + c], acc[mt], 0, 0, 0);
      }
  }
  char* ptc = (char*)pt1b;
  float bv1 = bt1[pr];
  #pragma unroll
  for (int mt = 0; mt < 4; ++mt) {
    #pragma unroll
    for (int i = 0; i < 4; ++i) {
      int p = mt*16 + g*4 + i;
      if (p < 49) {
        int yy = p / 7, xx = p % 7;
        int opix = (2*yy + py + 1)*16 + (2*xx + px + 1);
        *(_Float16*)(ptc + opix*40 + pr*2) = (_Float16)(fmaxf(acc[mt][i] + bv1, 0.f));
      }
    }
  }
  __syncthreads();
  {
    int qy = w >> 1, qx = w & 1;
    int kkt[4] = { qy*4 + qx, qy*4 + qx + 2, (qy+2)*4 + qx, (qy+2)*4 + qx + 2 };
    half2v wh[4][8];
    #pragma unroll
    for (int tt = 0; tt < 4; ++tt)
      #pragma unroll
      for (int q = 0; q < 8; ++q) {
        wh[tt][q].x = (_Float16)w2l[(2*q)*16 + kkt[tt]];
        wh[tt][q].y = (_Float16)w2l[(2*q+1)*16 + kkt[tt]];
      }
    float bv2 = bt2[0];
    #pragma unroll
    for (int k = 0; k < 4; ++k) {
      int j = l + k*64;
      if (j < 196) {
        int a = j / 14, bb = j % 14;
        int oy = 2*a + 1 - qy, ox = 2*bb + 1 - qx;
        int iy1 = a + 1 - qy, iy2 = a - qy;
        int ix1 = bb + 1 - qx, ix2 = bb - qx;
        int prw[4];
        prw[0] = (iy1 + 1)*16 + (ix1 + 1);
        prw[1] = (iy1 + 1)*16 + (ix2 + 1);
        prw[2] = (iy2 + 1)*16 + (ix1 + 1);
        prw[3] = (iy2 + 1)*16 + (ix2 + 1);
        float s = bv2;
        #pragma unroll
        for (int tt = 0; tt < 4; ++tt) {
          const char* base = ptc + prw[tt]*40;
          #pragma unroll
          for (int jj = 0; jj < 2; ++jj) {
            half4v a4 = *(const half4v*)(base + jj*8);
            half4v b4 = *(const half4v*)(base + 16 + jj*8);
            half2v a0 = {a4.x, a4.y}, a1 = {a4.z, a4.w};
            half2v b0 = {b4.x, b4.y}, b1 = {b4.z, b4.w};
            s = fdot2(a0, wh[tt][jj*2],     s);
            s = fdot2(a1, wh[tt][jj*2 + 1], s);
            s = fdot2(b0, wh[tt][jj*2 + 4], s);
            s = fdot2(b1, wh[tt][jj*2 + 5], s);
          }
        }
        outl[oy*28 + ox] = s;
      }
    }
  }
  __syncthreads();
  float* dst = out + (size_t)b*784;
  for (int i = t; i < 784; i += 256) dst[i] = outl[i];
}

extern "C" void kernel_launch(void* const* d_in, const int* in_sizes, int n_in,
                              void* d_out, int out_size, void* d_ws, size_t ws_size,
                              hipStream_t stream)
{
  const float* x    = (const float*)d_in[0];
  const float* c1w  = (const float*)d_in[1];
  const float* c1b  = (const float*)d_in[2];
  const float* c2w  = (const float*)d_in[3];
  const float* c2b  = (const float*)d_in[4];
  const float* r1w1 = (const float*)d_in[5];
  const float* r1w2 = (const float*)d_in[6];
  const float* fc1w = (const float*)d_in[7];
  const float* fc1b = (const float*)d_in[8];
  const float* fc2w = (const float*)d_in[9];
  const float* fc2b = (const float*)d_in[10];
  const float* emb  = (const float*)d_in[11];
  const float* nmat = (const float*)d_in[12];
  const float* mmat = (const float*)d_in[13];
  const float* fc3w = (const float*)d_in[14];
  const float* fc3b = (const float*)d_in[15];
  const float* fc4w = (const float*)d_in[16];
  const float* fc4b = (const float*)d_in[17];
  const float* r2w1 = (const float*)d_in[18];
  const float* r2w2 = (const float*)d_in[19];
  const float* t1w  = (const float*)d_in[20];
  const float* t1b  = (const float*)d_in[21];
  const float* t2w  = (const float*)d_in[22];
  const float* t2b  = (const float*)d_in[23];
  float* ws  = (float*)d_ws;
  float* out = (float*)d_out;

  ushort_t* hb   = (ushort_t*)(ws + OFF_HB);
  ushort_t* f1b  = (ushort_t*)(ws + OFF_F1B);
  ushort_t* f3b  = (ushort_t*)(ws + OFF_F3B);
  float*    z    = ws + OFF_Z;
  int*      idx  = (int*)(ws + OFF_IDX);
  ushort_t* zqb  = (ushort_t*)(ws + OFF_ZQB);
  float*    cnts = ws + OFF_CNT;
  float*    sums = ws + OFF_SUM;
  float*    loss = ws + OFF_LOSS;
  ushort_t* wencb  = (ushort_t*)(ws + OFF_WENC);
  ushort_t* wenc1b = (ushort_t*)(ws + OFF_WENC1);
  ushort_t* wt1b   = (ushort_t*)(ws + OFF_WT1B);
  ushort_t* wr1b   = (ushort_t*)(ws + OFF_WR1B);
  ushort_t* wr2b   = (ushort_t*)(ws + OFF_WR2B);
  ushort_t* w2b1   = (ushort_t*)(ws + OFF_W2B1);
  ushort_t* w2b2   = (ushort_t*)(ws + OFF_W2B2);
  ushort_t* fc1wb  = (ushort_t*)(ws + OFF_FC1WB);
  ushort_t* fc2wb  = (ushort_t*)(ws + OFF_FC2WB);
  ushort_t* fc3wb  = (ushort_t*)(ws + OFF_FC3WB);
  ushort_t* fc4wb  = (ushort_t*)(ws + OFF_FC4WB);
  float*    fc4bp  = ws + OFF_FC4BP;

  k_prep<<<3033, 256, 0, stream>>>(c1w, c2w, r1w1, r1w2, r2w1, r2w2, t1w,
                                   fc1w, fc2w, fc3w, fc4w, fc4b, ws);
  k_enc<<<NB, 256, 0, stream>>>(x, wenc1b, c1b, wencb, c2b, hb);
  k_res<<<NB, 256, 0, stream>>>(hb, wr1b, w2b1);
  k_mm<14, true, true><<<dim3(256, 1), 256, 0, stream>>>(hb, fc1wb, fc1b, f1b, 16384, 224, 1568);
  k_mm<2, false, false><<<dim3(256, 1), 256, 0, stream>>>(f1b, fc2wb, fc2b, z, 16384, 32, 224);
  k_vq_assign<<<4096, 256, 0, stream>>>(z, emb, zqb, idx, loss);
  k_vq_reduce<<<512, 64, 0, stream>>>(idx, z, cnts, sums);
  k_vq_final<<<1, 512, 0, stream>>>(cnts, sums, nmat, mmat, loss, out);
  k_mm<14, true, true><<<dim3(256, 1), 256, 0, stream>>>(zqb, fc3wb, fc3b, f3b, 16384, 224, 32);
  k_mm<14, true, true><<<dim3(256, 7), 256, 0, stream>>>(f3b, fc4wb, fc4bp, hb, 16384, 1568, 224);
  k_res<<<NB, 256, 0, stream>>>(hb, wr2b, w2b2);
  k_dec<<<NB, 256, 0, stream>>>(hb, wt1b, t1b, t2w, t2b, out);
}

// Round 7
// 895.461 us; speedup vs baseline: 1.1490x; 1.1490x over previous
//
#include <hip/hip_runtime.h>
#include <math.h>

#define NB 16384
typedef unsigned short ushort_t;
typedef unsigned int uint_t;
typedef __attribute__((ext_vector_type(8))) short short8;
typedef __attribute__((ext_vector_type(4))) float fx4;
typedef _Float16 half2v __attribute__((ext_vector_type(2)));
typedef _Float16 half4v __attribute__((ext_vector_type(4)));

// ---- ws float offsets ----
static const size_t OFF_HB    = 0;          // ushort[16384*1568] bf16, pixel-major [p49][ci32]
static const size_t OFF_F1B   = 12845056;   // ushort[16384*224]
static const size_t OFF_F3B   = 14680064;   // ushort[16384*224]
static const size_t OFF_Z     = 16515072;   // float[524288]
static const size_t OFF_IDX   = 17039360;   // int[16384]
static const size_t OFF_ZQB   = 17055744;   // ushort[524288]
static const size_t OFF_CNT   = 17317888;   // float[512]
static const size_t OFF_SUM   = 17318400;   // float[16384]
static const size_t OFF_LOSS  = 17334784;   // float[64]
static const size_t OFF_WENC  = 17334848;   // ushort[8192] [8kb][32co][32k]
static const size_t OFF_WT1B  = 17343040;   // ushort[8192] [16kk][16co][32ci]
static const size_t OFF_WR1B  = 17351232;   // ushort[18432]  [9][64][32]
static const size_t OFF_WR2B  = 17360448;   // ushort[18432]
static const size_t OFF_W2B1  = 17369664;   // ushort[2048]   [32][64]
static const size_t OFF_W2B2  = 17370688;   // ushort[2048]
static const size_t OFF_FC1WB = 17371712;   // ushort[351232] [224][1568 k-permuted]
static const size_t OFF_FC2WB = 17547328;   // ushort[7168]   [32][224]
static const size_t OFF_FC3WB = 17550912;   // ushort[7168]   [224][32]
static const size_t OFF_FC4WB = 17554496;   // ushort[351232] [1568 n-permuted][224]
static const size_t OFF_FC4BP = 17730112;   // float[1568] permuted fc4 bias

static __device__ __forceinline__ ushort_t f2bf(float f) {
  union { float f; uint_t u; } v; v.f = f;
  return (ushort_t)((v.u + 0x7fffu + ((v.u >> 16) & 1u)) >> 16);
}
static __device__ __forceinline__ float bf2f(ushort_t h) {
  union { uint_t u; float f; } v; v.u = ((uint_t)h) << 16;
  return v.f;
}
static __device__ __forceinline__ float fdot2(half2v a, half2v b, float c) {
#if __has_builtin(__builtin_amdgcn_fdot2)
  return __builtin_amdgcn_fdot2(a, b, c, false);
#else
  return c + (float)a.x * (float)b.x + (float)a.y * (float)b.y;
#endif
}

// Weight prep: transposes, permutes, fp32->bf16; zero loss accumulator.
__global__ __launch_bounds__(256) void k_prep(
    const float* __restrict__ c2w, const float* __restrict__ r1w1,
    const float* __restrict__ r1w2, const float* __restrict__ r2w1,
    const float* __restrict__ r2w2, const float* __restrict__ t1w,
    const float* __restrict__ fc1w, const float* __restrict__ fc2w,
    const float* __restrict__ fc3w, const float* __restrict__ fc4w,
    const float* __restrict__ fc4b, float* __restrict__ ws)
{
  int gid = blockIdx.x * 256 + threadIdx.x;
  if (gid == 0) ws[OFF_LOSS] = 0.f;
  if (gid >= 775712) return;
  ushort_t* wencb = (ushort_t*)(ws + OFF_WENC);
  ushort_t* wt1b  = (ushort_t*)(ws + OFF_WT1B);
  ushort_t* wr1b  = (ushort_t*)(ws + OFF_WR1B);
  ushort_t* wr2b  = (ushort_t*)(ws + OFF_WR2B);
  ushort_t* w2b1  = (ushort_t*)(ws + OFF_W2B1);
  ushort_t* w2b2  = (ushort_t*)(ws + OFF_W2B2);
  ushort_t* fc1wb = (ushort_t*)(ws + OFF_FC1WB);
  ushort_t* fc2wb = (ushort_t*)(ws + OFF_FC2WB);
  ushort_t* fc3wb = (ushort_t*)(ws + OFF_FC3WB);
  ushort_t* fc4wb = (ushort_t*)(ws + OFF_FC4WB);
  float*    fc4bp = ws + OFF_FC4BP;
  int i = gid;
  if (i < 8192) {            // conv2 MFMA weights: [kb=ky*2+k2][co32][k=kxs*16+ci]
    int kidx = i & 31, rest = i >> 5, co = rest & 31, kb = rest >> 5;
    int ky = kb >> 1, k2 = kb & 1, kxs = kidx >> 4, ci = kidx & 15;
    wencb[i] = f2bf(c2w[co*256 + ci*16 + ky*4 + 2*k2 + kxs]);
  } else if (i < 16384) {    // convT1 MFMA weights: [kk16][co16][ci32]
    int j = i - 8192, ci = j & 31, rest = j >> 5, co = rest & 15, kk = rest >> 4;
    wt1b[j] = f2bf(t1w[ci*256 + co*16 + kk]);
  } else if (i < 34816) {    // res1 w1 -> [kk][co][ci] bf16
    int j = i - 16384, ci = j & 31, r = j >> 5, co = r & 63, kk = r >> 6;
    wr1b[j] = f2bf(r1w1[co*288 + ci*9 + kk]);
  } else if (i < 53248) {    // res2 w1
    int j = i - 34816, ci = j & 31, r = j >> 5, co = r & 63, kk = r >> 6;
    wr2b[j] = f2bf(r2w1[co*288 + ci*9 + kk]);
  } else if (i < 55296) {    // res1 w2 [32][64] bf16
    int j = i - 53248; w2b1[j] = f2bf(r1w2[j]);
  } else if (i < 57344) {    // res2 w2
    int j = i - 55296; w2b2[j] = f2bf(r2w2[j]);
  } else if (i < 408576) {   // fc1 [224][1568], K permuted: k' = p*32+ci <- ci*49+p
    int j = i - 57344, n = j / 1568, k = j % 1568;
    int p = k >> 5, ci = k & 31;
    fc1wb[j] = f2bf(fc1w[n*1568 + ci*49 + p]);
  } else if (i < 415744) {   // fc2 [32][224]
    int j = i - 408576; fc2wb[j] = f2bf(fc2w[j]);
  } else if (i < 422912) {   // fc3 [224][32]
    int j = i - 415744; fc3wb[j] = f2bf(fc3w[j]);
  } else if (i < 774144) {   // fc4 [1568][224], N permuted: row p*32+ci <- ci*49+p
    int j = i - 422912, np = j / 224, k = j % 224;
    int p = np >> 5, ci = np & 31;
    fc4wb[j] = f2bf(fc4w[(ci*49 + p)*224 + k]);
  } else {                   // fc4 bias permuted
    int np = i - 774144, p = np >> 5, ci = np & 31;
    fc4bp[np] = fc4b[ci*49 + p];
  }
}

// Fused encoder: conv1(1->16,k4s2p1)+relu (VALU, weights in regs) -> conv2 (MFMA).
// Output pixel-major bf16 [p49][ci32]. One image/block, 256 threads. (round-5 measured version)
__global__ __launch_bounds__(256) void k_enc(const float* __restrict__ x,
    const float* __restrict__ w1, const float* __restrict__ b1,
    const ushort_t* __restrict__ wencb, const float* __restrict__ b2,
    ushort_t* __restrict__ hb)
{
  __shared__ float xin[30][32];          // x padded
  __shared__ ushort_t ph1b[256*24];      // [prow=piy*16+pix][ci16] bf16, 48B row stride
  __shared__ ushort_t outl[1568];        // [p49][co32]
  int b = blockIdx.x, t = threadIdx.x, l = t & 63, w = t >> 6;
  int pr = l & 15, g = l >> 4;
  // conv1 weights -> registers (co invariant per thread)
  int co16 = t & 15;
  float wr1v[16];
  #pragma unroll
  for (int kk = 0; kk < 16; ++kk) wr1v[kk] = w1[co16*16 + kk];
  float bv1 = b1[co16];
  // conv2 B-frags
  short8 bf[8][2];
  #pragma unroll
  for (int kb = 0; kb < 8; ++kb)
    #pragma unroll
    for (int nt = 0; nt < 2; ++nt)
      bf[kb][nt] = *(const short8*)(wencb + (size_t)(kb*32 + nt*16 + pr)*32 + g*8);
  uint_t* pz = (uint_t*)ph1b;
  for (int i = t; i < 3072; i += 256) pz[i] = 0;
  float* xp = &xin[0][0];
  for (int i = t; i < 960; i += 256) xp[i] = 0.f;
  __syncthreads();
  const float* xb = x + (size_t)b*784;
  for (int i = t; i < 784; i += 256) xin[i/28 + 1][i%28 + 1] = xb[i];
  __syncthreads();
  // conv1: lanes 0-15 share pixel -> xin broadcast; weights from registers
  char* phc = (char*)ph1b;
  for (int i = t; i < 3136; i += 256) {
    int p = i >> 4, oy = p/14, ox = p%14;
    float acc = bv1;
    #pragma unroll
    for (int ky = 0; ky < 4; ++ky)
      #pragma unroll
      for (int kx = 0; kx < 4; ++kx)
        acc += xin[2*oy+ky][2*ox+kx] * wr1v[ky*4+kx];
    *(ushort_t*)(phc + ((oy+1)*16 + (ox+1))*48 + co16*2) = f2bf(fmaxf(acc, 0.f));
  }
  __syncthreads();
  // conv2 MFMA: wave w = M-tile; 8 k-blocks, 2 n-tiles
  int p = w*16 + pr; if (p > 48) p = 48;
  int oy = p/7, ox = p%7;
  fx4 acc2[2];
  acc2[0] = (fx4){0.f,0.f,0.f,0.f}; acc2[1] = (fx4){0.f,0.f,0.f,0.f};
  #pragma unroll
  for (int kb = 0; kb < 8; ++kb) {
    int ky = kb >> 1, k2 = kb & 1;
    int prow = (2*oy + ky)*16 + 2*ox + 2*k2 + (g >> 1);
    short8 afr = *(const short8*)(phc + prow*48 + (g & 1)*16);
    acc2[0] = __builtin_amdgcn_mfma_f32_16x16x32_bf16(afr, bf[kb][0], acc2[0], 0, 0, 0);
    acc2[1] = __builtin_amdgcn_mfma_f32_16x16x32_bf16(afr, bf[kb][1], acc2[1], 0, 0, 0);
  }
  #pragma unroll
  for (int nt = 0; nt < 2; ++nt) {
    int co = nt*16 + pr;
    float bv = b2[co];
    #pragma unroll
    for (int i = 0; i < 4; ++i) {
      int pix = w*16 + g*4 + i;
      if (pix < 49) outl[pix*32 + co] = f2bf(acc2[nt][i] + bv);
    }
  }
  __syncthreads();
  uint_t* dst = (uint_t*)(hb + (size_t)b*1568);
  const uint_t* so = (const uint_t*)outl;
  for (int j = t; j < 784; j += 256) dst[j] = so[j];
}

// MFMA residual stack, pixel-major in/out bf16 [p49][ci32], in-place.
__global__ __launch_bounds__(256) void k_res(ushort_t* __restrict__ hb,
    const ushort_t* __restrict__ wrb, const ushort_t* __restrict__ w2b)
{
  __shared__ ushort_t pinT[3456];   // [pp=108][ci=32], swizzled (64B rows)
  __shared__ ushort_t rl[4096];     // [pix=64][co=64], swizzled (128B rows)
  __shared__ ushort_t hrawb[1568];  // raw copy, [p][ci]
  __shared__ ushort_t outl[1568];   // [p][ci]
  int b = blockIdx.x, t = threadIdx.x, l = t & 63, w = t >> 6, g = l >> 4;

  short8 bfr[9];
  #pragma unroll
  for (int o = 0; o < 9; ++o)
    bfr[o] = *(const short8*)(wrb + (size_t)(o*64 + w*16 + (l & 15))*32 + g*8);

  uint_t* pz = (uint_t*)pinT;
  for (int i = t; i < 1728; i += 256) pz[i] = 0;
  __syncthreads();

  const uint_t* src = (const uint_t*)(hb + (size_t)b*1568);
  char* pinc = (char*)pinT;
  for (int j = t; j < 784; j += 256) {
    uint_t u = src[j];
    ((uint_t*)hrawb)[j] = u;
    uint_t ur = u;
    ur = (ur & 0x80000000u) ? (ur & 0x0000ffffu) : ur;   // relu hi half
    ur = (ur & 0x8000u)     ? (ur & 0xffff0000u) : ur;   // relu lo half
    int p = j >> 4, c2 = (j & 15) << 1;
    int ppix = (p/7 + 1)*12 + (p%7) + 1;
    int byte = ((ppix << 6) + (c2 << 1)) ^ ((ppix & 6) << 3);
    *(uint_t*)(pinc + byte) = ur;
  }
  __syncthreads();

  fx4 acc[4];
  #pragma unroll
  for (int mt = 0; mt < 4; ++mt) acc[mt] = (fx4){0.f, 0.f, 0.f, 0.f};
  int pb[4];
  #pragma unroll
  for (int mt = 0; mt < 4; ++mt) {
    int p = mt*16 + (l & 15); if (p > 48) p = 48;
    pb[mt] = (p / 7)*12 + (p % 7);
  }
  #pragma unroll
  for (int mt = 0; mt < 4; ++mt) {
    #pragma unroll
    for (int o = 0; o < 9; ++o) {
      int ppix = pb[mt] + (o / 3)*12 + (o % 3);
      int byte = ((ppix << 6) + (g << 4)) ^ ((ppix & 6) << 3);
      short8 afr = *(const short8*)(pinc + byte);
      acc[mt] = __builtin_amdgcn_mfma_f32_16x16x32_bf16(afr, bfr[o], acc[mt], 0, 0, 0);
    }
  }
  char* rlc = (char*)rl;
  #pragma unroll
  for (int mt = 0; mt < 4; ++mt) {
    #pragma unroll
    for (int i = 0; i < 4; ++i) {
      int pixr = mt*16 + g*4 + i;
      int co2 = w*16 + (l & 15);
      int byte = ((pixr << 7) + (co2 << 1)) ^ ((pixr & 7) << 4);
      *(ushort_t*)(rlc + byte) = f2bf(fmaxf(acc[mt][i], 0.f));
    }
  }
  __syncthreads();

  fx4 a1[2];
  a1[0] = (fx4){0.f,0.f,0.f,0.f}; a1[1] = (fx4){0.f,0.f,0.f,0.f};
  int prr = w*16 + (l & 15);
  #pragma unroll
  for (int kf = 0; kf < 2; ++kf) {
    int byte = ((prr << 7) + (kf << 6) + (g << 4)) ^ ((prr & 7) << 4);
    short8 ar = *(const short8*)(rlc + byte);
    #pragma unroll
    for (int nt = 0; nt < 2; ++nt) {
      short8 br = *(const short8*)(w2b + (size_t)(nt*16 + (l & 15))*64 + kf*32 + g*8);
      a1[nt] = __builtin_amdgcn_mfma_f32_16x16x32_bf16(ar, br, a1[nt], 0, 0, 0);
    }
  }
  #pragma unroll
  for (int nt = 0; nt < 2; ++nt) {
    #pragma unroll
    for (int i = 0; i < 4; ++i) {
      int pix = w*16 + g*4 + i;
      if (pix < 49) {
        int co2 = nt*16 + (l & 15);
        int idx2 = pix*32 + co2;
        float v = bf2f(hrawb[idx2]) + a1[nt][i];
        outl[idx2] = f2bf(fmaxf(v, 0.f));
      }
    }
  }
  __syncthreads();
  uint_t* dst = (uint_t*)(hb + (size_t)b*1568);
  const uint_t* so = (const uint_t*)outl;
  for (int j = t; j < 784; j += 256) dst[j] = so[j];
}

// MFMA GEMM with A-prefetch: C[M,N] = A[M,K](bf16) * Wb[N,K]^T + bias.
template<int BNF, bool OUTBF16, bool RELU>
__global__ __launch_bounds__(256) void k_mm(const ushort_t* __restrict__ A,
    const ushort_t* __restrict__ Wb, const float* __restrict__ bias,
    void* __restrict__ C, int M, int N, int K)
{
  __shared__ ushort_t As[2048];   // [64][32] bf16, swizzled (64B rows)
  int t = threadIdx.x, l = t & 63, w = t >> 6, g = l >> 4;
  int m0 = blockIdx.x * 64, n0 = blockIdx.y * (BNF * 16);
  fx4 acc[BNF];
  #pragma unroll
  for (int nt = 0; nt < BNF; ++nt) acc[nt] = (fx4){0.f, 0.f, 0.f, 0.f};
  char* asc = (char*)As;
  int srow = t >> 2, sks = (t & 3) * 8;
  int sbyte = ((srow << 6) + (sks << 1)) ^ ((srow & 6) << 3);
  int arow = w*16 + (l & 15);
  int abyte = ((arow << 6) + (g << 4)) ^ ((arow & 6) << 3);
  const ushort_t* ap = A + (size_t)(m0 + srow)*K + sks;
  short8 av = *(const short8*)ap;
  for (int k0 = 0; k0 < K; k0 += 32) {
    __syncthreads();
    *(short8*)(asc + sbyte) = av;
    __syncthreads();
    if (k0 + 32 < K) av = *(const short8*)(ap + k0 + 32);   // prefetch next
    short8 afr = *(const short8*)(asc + abyte);
    #pragma unroll
    for (int nt = 0; nt < BNF; ++nt) {
      short8 bfr = *(const short8*)(Wb + (size_t)(n0 + nt*16 + (l & 15))*K + k0 + g*8);
      acc[nt] = __builtin_amdgcn_mfma_f32_16x16x32_bf16(afr, bfr, acc[nt], 0, 0, 0);
    }
  }
  #pragma unroll
  for (int nt = 0; nt < BNF; ++nt) {
    int col = n0 + nt*16 + (l & 15);
    float bv = bias[col];
    #pragma unroll
    for (int i = 0; i < 4; ++i) {
      int row = m0 + w*16 + g*4 + i;
      float v = acc[nt][i] + bv;
      if (RELU) v = fmaxf(v, 0.f);
      if (OUTBF16) ((ushort_t*)C)[(size_t)row*N + col] = f2bf(v);
      else         ((float*)C)[(size_t)row*N + col] = v;
    }
  }
}

// VQ assign: LDS-resident codebook. 256 blocks x 512 threads; 64 rows/block;
// 8 q-groups x 64 codes/thread; emb LDS reads are wave-broadcast (conflict-free).
__global__ __launch_bounds__(512) void k_vq_assign(const float* __restrict__ z,
    const float* __restrict__ emb, ushort_t* __restrict__ zqb, int* __restrict__ idx,
    float* __restrict__ loss)
{
  __shared__ float embL[16384];     // [512][32] fp32 codebook
  __shared__ float esq[512];
  __shared__ float zL[64*33];       // [64][33] padded (bank-spread)
  __shared__ float bestdL[8][64];
  __shared__ int   bestiL[8][64];
  int t = threadIdx.x, r = t & 63, q = t >> 6;
  int n0 = blockIdx.x * 64;
  // stage emb (coalesced float4)
  fx4* embL4 = (fx4*)embL;
  const fx4* emb4 = (const fx4*)emb;
  #pragma unroll
  for (int j = 0; j < 8; ++j) embL4[t + j*512] = emb4[t + j*512];
  // stage z rows (4 floats/thread into padded zL)
  {
    int f0 = t*4;
    int row = f0 >> 5, col = f0 & 31;
    const float4 v = *(const float4*)&z[(size_t)n0*32 + f0];
    zL[row*33 + col]   = v.x; zL[row*33 + col+1] = v.y;
    zL[row*33 + col+2] = v.z; zL[row*33 + col+3] = v.w;
  }
  __syncthreads();
  // esq (one-time; conflict cost negligible)
  {
    float s = 0.f;
    const fx4* ep = (const fx4*)&embL[t*32 & 16383];
    #pragma unroll
    for (int j2 = 0; j2 < 8; ++j2) { fx4 v = ep[j2]; s += v.x*v.x + v.y*v.y + v.z*v.z + v.w*v.w; }
    esq[t & 511] = s;
  }
  // z row -> registers
  float zv[32];
  #pragma unroll
  for (int k = 0; k < 32; ++k) zv[k] = zL[r*33 + k];
  __syncthreads();
  // scan 64 codes (q-group); d' = esq - 2*dot (zz is row-constant, argmin-invariant)
  float best = 3.4e38f; int bi = 0;
  for (int j = 0; j < 64; ++j) {
    int e = q*64 + j;
    const fx4* ep = (const fx4*)&embL[e*32];
    float dot = 0.f;
    #pragma unroll
    for (int k2 = 0; k2 < 8; ++k2) {
      fx4 v = ep[k2];
      dot += zv[4*k2]*v.x + zv[4*k2+1]*v.y + zv[4*k2+2]*v.z + zv[4*k2+3]*v.w;
    }
    float d = esq[e] - 2.f*dot;
    if (d < best) { best = d; bi = e; }
  }
  bestdL[q][r] = best; bestiL[q][r] = bi;
  __syncthreads();
  // combine 8 candidates per row (first-occurrence tie-break), write idx
  if (t < 64) {
    float bb = bestdL[0][r]; int bbi = bestiL[0][r];
    #pragma unroll
    for (int j = 1; j < 8; ++j) {
      float d = bestdL[j][r]; int di = bestiL[j][r];
      if (d < bb || (d == bb && di < bbi)) { bb = d; bbi = di; }
    }
    idx[n0 + r] = bbi;
    bestiL[0][r] = bbi;
  }
  __syncthreads();
  // zq gather (bf16) + commit loss: waves 0-3, thread = (row r, dim-slice q*8..+8)
  if (t < 256) {
    int q4 = t >> 6;
    int n = n0 + r;
    int bsel = bestiL[0][r];
    float ls = 0.f;
    uint_t ow[4];
    #pragma unroll
    for (int h = 0; h < 4; ++h) {
      float e0 = embL[bsel*32 + q4*8 + 2*h];
      float e1 = embL[bsel*32 + q4*8 + 2*h + 1];
      float d0 = e0 - zv[q4*8 + 2*h], d1 = e1 - zv[q4*8 + 2*h + 1];
      ls += d0*d0 + d1*d1;
      ow[h] = (uint_t)f2bf(e0) | ((uint_t)f2bf(e1) << 16);
    }
    uint_t* zo = (uint_t*)(zqb + (size_t)n*32) + q4*4;
    #pragma unroll
    for (int h = 0; h < 4; ++h) zo[h] = ow[h];
    #pragma unroll
    for (int m = 32; m >= 1; m >>= 1) ls += __shfl_xor(ls, m);
    if (r == 0) atomicAdd(loss, ls);
  }
}

// Per-code segment reduction: counts[e], sums[e][32]. One wave per code.
__global__ __launch_bounds__(64) void k_vq_reduce(const int* __restrict__ idx,
    const float* __restrict__ z, float* __restrict__ counts, float* __restrict__ sums)
{
  int e = blockIdx.x, t = threadIdx.x;
  float cnt = 0.f, sv[32];
  #pragma unroll
  for (int k = 0; k < 32; ++k) sv[k] = 0.f;
  for (int n = t; n < 16384; n += 64) {
    if (idx[n] == e) {
      cnt += 1.f;
      const float4* zp = (const float4*)&z[n*32];
      #pragma unroll
      for (int q = 0; q < 8; ++q) {
        float4 v = zp[q];
        sv[4*q] += v.x; sv[4*q+1] += v.y; sv[4*q+2] += v.z; sv[4*q+3] += v.w;
      }
    }
  }
  #pragma unroll
  for (int m = 32; m >= 1; m >>= 1) {
    cnt += __shfl_xor(cnt, m);
    #pragma unroll
    for (int k = 0; k < 32; ++k) sv[k] += __shfl_xor(sv[k], m);
  }
  if (t == 0) {
    counts[e] = cnt;
    #pragma unroll
    for (int k = 0; k < 32; ++k) sums[e*32 + k] = sv[k];
  }
}

// EMA update, emb_new, perplexity, losses.
__global__ __launch_bounds__(512) void k_vq_final(const float* __restrict__ counts,
    const float* __restrict__ sums, const float* __restrict__ n_mat,
    const float* __restrict__ m_mat, const float* __restrict__ loss,
    float* __restrict__ out)
{
  __shared__ float red[8];
  int t = threadIdx.x;
  float c = counts[t];
  float nn = n_mat[t]*0.99f + c*0.01f;
  #pragma unroll
  for (int k = 0; k < 32; ++k) {
    float mn = m_mat[t*32+k]*0.99f + sums[t*32+k]*0.01f;
    out[12845059 + t*32 + k] = mn / nn;
  }
  float em = c * (1.f/16384.f);
  float ht = em * logf(em + 1e-10f);
  #pragma unroll
  for (int m = 32; m >= 1; m >>= 1) ht += __shfl_xor(ht, m);
  if ((t & 63) == 0) red[t >> 6] = ht;
  __syncthreads();
  if (t == 0) {
    float H = 0.f;
    #pragma unroll
    for (int i = 0; i < 8; ++i) H += red[i];
    float q = loss[0] * (1.f/524288.f);
    out[12845056] = q;           // quant_loss
    out[12845057] = q;           // commit_loss (BETA = 1.0)
    out[12845058] = expf(-H);    // perplexity
  }
}

// Fused decoder: convT1 (MFMA, parity/wave) -> relu -> convT2 (fdot2 on f16).
// Input pixel-major bf16 [p49][ci32]; output fp32 [784]. One image/block.
__global__ __launch_bounds__(256) void k_dec(const ushort_t* __restrict__ h5,
    const ushort_t* __restrict__ wt1b, const float* __restrict__ bt1,
    const float* __restrict__ wt2, const float* __restrict__ bt2,
    float* __restrict__ out)
{
  __shared__ ushort_t pinT[3456];     // h5 [ppix=108][ci=32] swizzled (64B rows)
  __shared__ ushort_t pt1b[256*20];   // t1 [opix=(iy+1)*16+(ix+1)][ci16] f16, 40B stride
  __shared__ float w2l[256];          // convT2 weights [ci][kk] fp32
  __shared__ float outl[784];
  int b = blockIdx.x, t = threadIdx.x, l = t & 63, w = t >> 6;
  int pr = l & 15, g = l >> 4;
  int py = w >> 1, px = w & 1;        // wave parity
  short8 bfr[4];
  #pragma unroll
  for (int r = 0; r < 2; ++r)
    #pragma unroll
    for (int c = 0; c < 2; ++c) {
      int kk = (3 - py - 2*r)*4 + (3 - px - 2*c);
      bfr[r*2 + c] = *(const short8*)(wt1b + (size_t)(kk*16 + pr)*32 + g*8);
    }
  uint_t* pz = (uint_t*)pinT;
  for (int i = t; i < 1728; i += 256) pz[i] = 0;
  uint_t* qz = (uint_t*)pt1b;
  for (int i = t; i < 2560; i += 256) qz[i] = 0;
  if (t < 256) w2l[t] = wt2[t];
  __syncthreads();
  const uint_t* src = (const uint_t*)(h5 + (size_t)b*1568);
  char* pinc = (char*)pinT;
  for (int j = t; j < 784; j += 256) {
    uint_t u = src[j];
    int p = j >> 4, c2 = (j & 15) << 1;
    int ppix = (p/7 + 1)*12 + (p%7) + 1;
    int byte = ((ppix << 6) + (c2 << 1)) ^ ((ppix & 6) << 3);
    *(uint_t*)(pinc + byte) = u;
  }
  __syncthreads();
  fx4 acc[4];
  #pragma unroll
  for (int mt = 0; mt < 4; ++mt) acc[mt] = (fx4){0.f, 0.f, 0.f, 0.f};
  int pb[4];
  #pragma unroll
  for (int mt = 0; mt < 4; ++mt) {
    int p = mt*16 + pr; if (p > 48) p = 48;
    pb[mt] = (p / 7)*12 + (p % 7);
  }
  #pragma unroll
  for (int mt = 0; mt < 4; ++mt) {
    #pragma unroll
    for (int r = 0; r < 2; ++r)
      #pragma unroll
      for (int c = 0; c < 2; ++c) {
        int ppix = pb[mt] + (py + r)*12 + (px + c);
        int byte = ((ppix << 6) + (g << 4)) ^ ((ppix & 6) << 3);
        short8 afr = *(const short8*)(pinc + byte);
        acc[mt] = __builtin_amdgcn_mfma_f32_16x16x32_bf16(afr, bfr[r*2 + c], acc[mt], 0, 0, 0);
      }
  }
  char* ptc = (char*)pt1b;
  float bv1 = bt1[pr];
  #pragma unroll
  for (int mt = 0; mt < 4; ++mt) {
    #pragma unroll
    for (int i = 0; i < 4; ++i) {
      int p = mt*16 + g*4 + i;
      if (p < 49) {
        int yy = p / 7, xx = p % 7;
        int opix = (2*yy + py + 1)*16 + (2*xx + px + 1);
        *(_Float16*)(ptc + opix*40 + pr*2) = (_Float16)(fmaxf(acc[mt][i] + bv1, 0.f));
      }
    }
  }
  __syncthreads();
  {
    int qy = w >> 1, qx = w & 1;
    int kkt[4] = { qy*4 + qx, qy*4 + qx + 2, (qy+2)*4 + qx, (qy+2)*4 + qx + 2 };
    half2v wh[4][8];
    #pragma unroll
    for (int tt = 0; tt < 4; ++tt)
      #pragma unroll
      for (int q = 0; q < 8; ++q) {
        wh[tt][q].x = (_Float16)w2l[(2*q)*16 + kkt[tt]];
        wh[tt][q].y = (_Float16)w2l[(2*q+1)*16 + kkt[tt]];
      }
    float bv2 = bt2[0];
    #pragma unroll
    for (int k = 0; k < 4; ++k) {
      int j = l + k*64;
      if (j < 196) {
        int a = j / 14, bb = j % 14;
        int oy = 2*a + 1 - qy, ox = 2*bb + 1 - qx;
        int iy1 = a + 1 - qy, iy2 = a - qy;
        int ix1 = bb + 1 - qx, ix2 = bb - qx;
        int prw[4];
        prw[0] = (iy1 + 1)*16 + (ix1 + 1);
        prw[1] = (iy1 + 1)*16 + (ix2 + 1);
        prw[2] = (iy2 + 1)*16 + (ix1 + 1);
        prw[3] = (iy2 + 1)*16 + (ix2 + 1);
        float s = bv2;
        #pragma unroll
        for (int tt = 0; tt < 4; ++tt) {
          const char* base = ptc + prw[tt]*40;
          #pragma unroll
          for (int jj = 0; jj < 2; ++jj) {
            half4v a4 = *(const half4v*)(base + jj*8);
            half4v b4 = *(const half4v*)(base + 16 + jj*8);
            half2v a0 = {a4.x, a4.y}, a1 = {a4.z, a4.w};
            half2v b0 = {b4.x, b4.y}, b1 = {b4.z, b4.w};
            s = fdot2(a0, wh[tt][jj*2],     s);
            s = fdot2(a1, wh[tt][jj*2 + 1], s);
            s = fdot2(b0, wh[tt][jj*2 + 4], s);
            s = fdot2(b1, wh[tt][jj*2 + 5], s);
          }
        }
        outl[oy*28 + ox] = s;
      }
    }
  }
  __syncthreads();
  float* dst = out + (size_t)b*784;
  for (int i = t; i < 784; i += 256) dst[i] = outl[i];
}

extern "C" void kernel_launch(void* const* d_in, const int* in_sizes, int n_in,
                              void* d_out, int out_size, void* d_ws, size_t ws_size,
                              hipStream_t stream)
{
  const float* x    = (const float*)d_in[0];
  const float* c1w  = (const float*)d_in[1];
  const float* c1b  = (const float*)d_in[2];
  const float* c2w  = (const float*)d_in[3];
  const float* c2b  = (const float*)d_in[4];
  const float* r1w1 = (const float*)d_in[5];
  const float* r1w2 = (const float*)d_in[6];
  const float* fc1w = (const float*)d_in[7];
  const float* fc1b = (const float*)d_in[8];
  const float* fc2w = (const float*)d_in[9];
  const float* fc2b = (const float*)d_in[10];
  const float* emb  = (const float*)d_in[11];
  const float* nmat = (const float*)d_in[12];
  const float* mmat = (const float*)d_in[13];
  const float* fc3w = (const float*)d_in[14];
  const float* fc3b = (const float*)d_in[15];
  const float* fc4w = (const float*)d_in[16];
  const float* fc4b = (const float*)d_in[17];
  const float* r2w1 = (const float*)d_in[18];
  const float* r2w2 = (const float*)d_in[19];
  const float* t1w  = (const float*)d_in[20];
  const float* t1b  = (const float*)d_in[21];
  const float* t2w  = (const float*)d_in[22];
  const float* t2b  = (const float*)d_in[23];
  float* ws  = (float*)d_ws;
  float* out = (float*)d_out;

  ushort_t* hb   = (ushort_t*)(ws + OFF_HB);
  ushort_t* f1b  = (ushort_t*)(ws + OFF_F1B);
  ushort_t* f3b  = (ushort_t*)(ws + OFF_F3B);
  float*    z    = ws + OFF_Z;
  int*      idx  = (int*)(ws + OFF_IDX);
  ushort_t* zqb  = (ushort_t*)(ws + OFF_ZQB);
  float*    cnts = ws + OFF_CNT;
  float*    sums = ws + OFF_SUM;
  float*    loss = ws + OFF_LOSS;
  ushort_t* wencb  = (ushort_t*)(ws + OFF_WENC);
  ushort_t* wt1b   = (ushort_t*)(ws + OFF_WT1B);
  ushort_t* wr1b   = (ushort_t*)(ws + OFF_WR1B);
  ushort_t* wr2b   = (ushort_t*)(ws + OFF_WR2B);
  ushort_t* w2b1   = (ushort_t*)(ws + OFF_W2B1);
  ushort_t* w2b2   = (ushort_t*)(ws + OFF_W2B2);
  ushort_t* fc1wb  = (ushort_t*)(ws + OFF_FC1WB);
  ushort_t* fc2wb  = (ushort_t*)(ws + OFF_FC2WB);
  ushort_t* fc3wb  = (ushort_t*)(ws + OFF_FC3WB);
  ushort_t* fc4wb  = (ushort_t*)(ws + OFF_FC4WB);
  float*    fc4bp  = ws + OFF_FC4BP;

  k_prep<<<3031, 256, 0, stream>>>(c2w, r1w1, r1w2, r2w1, r2w2, t1w,
                                   fc1w, fc2w, fc3w, fc4w, fc4b, ws);
  k_enc<<<NB, 256, 0, stream>>>(x, c1w, c1b, wencb, c2b, hb);
  k_res<<<NB, 256, 0, stream>>>(hb, wr1b, w2b1);
  k_mm<14, true, true><<<dim3(256, 1), 256, 0, stream>>>(hb, fc1wb, fc1b, f1b, 16384, 224, 1568);
  k_mm<2, false, false><<<dim3(256, 1), 256, 0, stream>>>(f1b, fc2wb, fc2b, z, 16384, 32, 224);
  k_vq_assign<<<256, 512, 0, stream>>>(z, emb, zqb, idx, loss);
  k_vq_reduce<<<512, 64, 0, stream>>>(idx, z, cnts, sums);
  k_vq_final<<<1, 512, 0, stream>>>(cnts, sums, nmat, mmat, loss, out);
  k_mm<14, true, true><<<dim3(256, 1), 256, 0, stream>>>(zqb, fc3wb, fc3b, f3b, 16384, 224, 32);
  k_mm<14, true, true><<<dim3(256, 7), 256, 0, stream>>>(f3b, fc4wb, fc4bp, hb, 16384, 1568, 224);
  k_res<<<NB, 256, 0, stream>>>(hb, wr2b, w2b2);
  k_dec<<<NB, 256, 0, stream>>>(hb, wt1b, t1b, t2w, t2b, out);
}